// Round 1
// baseline (171.219 us; speedup 1.0000x reference)
//
#include <hip/hip_runtime.h>

// ---------------------------------------------------------------------------
// DeBERTa-v2 disentangled self-attention, MI355X (gfx950)
// B=2, L=1024, D=1024, H=16, HEAD=64, ATT_SPAN=256 (pos dim 512), scale=sqrt(192)
// ---------------------------------------------------------------------------

typedef short s8v __attribute__((ext_vector_type(8)));
typedef short s4v __attribute__((ext_vector_type(4)));
typedef float f32x4 __attribute__((ext_vector_type(4)));
typedef float f4v __attribute__((ext_vector_type(4)));

#define QK_SCALE 0.26864243f   // 192^(-1/4); folded so all score terms get /sqrt(192)

__device__ __forceinline__ unsigned short f2bf(float f) {
  unsigned u = __builtin_bit_cast(unsigned, f);
  u += 0x7fffu + ((u >> 16) & 1u);          // RNE
  return (unsigned short)(u >> 16);
}
__device__ __forceinline__ float bf2f(unsigned short h) {
  unsigned u = ((unsigned)h) << 16;
  return __builtin_bit_cast(float, u);
}

__device__ __forceinline__ void gload_lds16(const void* g, void* l) {
  __builtin_amdgcn_global_load_lds(
      (const __attribute__((address_space(1))) void*)g,
      (__attribute__((address_space(3))) void*)l, 16, 0, 0);
}

// ---------------------------------------------------------------------------
// prep: f32->bf16 conversions, bucket table, mask bias
//   Abf [2560,1024] = [hidden(2048); rel_emb(512)]
//   Wbf: Wq,Wk,Wv each [1024,1024]
//   Tt[2047]: clip(bucket(rel)+256, 0, 511) for rel in [-1023,1023]
//   mbias[2048]: mask>0 ? 0 : -1e9
// ---------------------------------------------------------------------------
__global__ __launch_bounds__(256) void prep_kernel(
    const float* __restrict__ hidden, const float* __restrict__ rel,
    const float* __restrict__ Wq, const float* __restrict__ Wk,
    const float* __restrict__ Wv, const int* __restrict__ mask,
    short* __restrict__ Abf, short* __restrict__ Wbf,
    float* __restrict__ mbias, short* __restrict__ Tt) {
  int idx = blockIdx.x * 256 + threadIdx.x;
  const int NCONV = 1441792;  // (2560*1024 + 3*1024*1024)/4 float4s
  if (idx < NCONV) {
    const float* src; short* dst; int off;
    if (idx < 524288) { src = hidden; dst = Abf; off = idx; }
    else if (idx < 655360) { src = rel; dst = Abf + 2048 * 1024; off = idx - 524288; }
    else {
      int j = idx - 655360;
      int w = j / 262144; off = j - w * 262144;
      src = (w == 0) ? Wq : (w == 1) ? Wk : Wv;
      dst = Wbf + w * 1048576;
    }
    f4v v = ((const f4v*)src)[off];
    s4v o;
    o[0] = (short)f2bf(v[0]); o[1] = (short)f2bf(v[1]);
    o[2] = (short)f2bf(v[2]); o[3] = (short)f2bf(v[3]);
    ((s4v*)dst)[off] = o;
  } else {
    int j = idx - NCONV;
    if (j < 2047) {
      int r = j - 1023;
      float fr = (float)r;
      float sign = (r > 0) ? 1.f : ((r < 0) ? -1.f : 0.f);
      float abs_pos = (r < 128 && r > -128) ? 127.f : fabsf(fr);
      const float logc = 1.3843393245589053f;  // f32(log(511/128))
      float log_pos = ceilf(logf(abs_pos * (1.f / 128.f)) / logc * 127.f) + 128.f;
      float bucket = (abs_pos <= 128.f) ? fr : log_pos * sign;
      int bi = (int)bucket + 256;
      bi = bi < 0 ? 0 : (bi > 511 ? 511 : bi);
      Tt[j] = (short)bi;
    } else if (j < 4095) {
      int m = j - 2047;
      mbias[m] = (mask[m] > 0) ? 0.f : -1e9f;
    }
  }
}

// ---------------------------------------------------------------------------
// gemm_qkv: C[m,n] = (sum_k A[m,k]*W[n,k] + bias[n]) * scale, bf16 out
//   A [2560,1024] bf16; W [1024,1024] bf16 (row n = weight row, torch y=xW^T)
//   z=0: Q (scale=QK_SCALE), z=1: K (scale=QK_SCALE), z=2: V (scale=1)
//   128x128 tile, BK=64, 4 waves (2x2), global_load_lds width 16, linear LDS
// ---------------------------------------------------------------------------
__global__ __launch_bounds__(256) void gemm_qkv(
    const short* __restrict__ Abf, const short* __restrict__ Wbf,
    const float* __restrict__ bq, const float* __restrict__ bk,
    const float* __restrict__ bv,
    short* __restrict__ Qc, short* __restrict__ Kc, short* __restrict__ Vc) {
  __shared__ short As[128 * 64];
  __shared__ short Bs[128 * 64];
  int tid = threadIdx.x;
  int wid = tid >> 6, lane = tid & 63;
  int lr = lane & 15, lg = lane >> 4;
  int wr = wid >> 1, wc = wid & 1;
  int z = blockIdx.z;
  const short* W = Wbf + z * 1048576;
  const float* bias = (z == 0) ? bq : (z == 1) ? bk : bv;
  short* C = (z == 0) ? Qc : (z == 1) ? Kc : Vc;
  float scale = (z == 2) ? 1.f : QK_SCALE;
  int brow = blockIdx.y * 128;
  int bcol = blockIdx.x * 128;

  f32x4 acc[4][4];
  for (int i = 0; i < 4; i++)
    for (int j = 0; j < 4; j++) acc[i][j] = (f32x4){0.f, 0.f, 0.f, 0.f};

  for (int k0 = 0; k0 < 1024; k0 += 64) {
    for (int i = 0; i < 4; i++) {
      int n = i * 256 + wid * 64 + lane;
      const short* gA = Abf + (size_t)(brow + (n >> 3)) * 1024 + k0 + (n & 7) * 8;
      gload_lds16(gA, &As[(i * 256 + wid * 64) * 8]);
      const short* gB = W + (size_t)(bcol + (n >> 3)) * 1024 + k0 + (n & 7) * 8;
      gload_lds16(gB, &Bs[(i * 256 + wid * 64) * 8]);
    }
    __syncthreads();
    for (int ks = 0; ks < 2; ks++) {
      s8v af[4], bfv[4];
      for (int mi = 0; mi < 4; mi++)
        af[mi] = *(const s8v*)&As[(wr * 64 + mi * 16 + lr) * 64 + ks * 32 + lg * 8];
      for (int ni = 0; ni < 4; ni++)
        bfv[ni] = *(const s8v*)&Bs[(wc * 64 + ni * 16 + lr) * 64 + ks * 32 + lg * 8];
      for (int mi = 0; mi < 4; mi++)
        for (int ni = 0; ni < 4; ni++)
          acc[mi][ni] = __builtin_amdgcn_mfma_f32_16x16x32_bf16(
              af[mi], bfv[ni], acc[mi][ni], 0, 0, 0);
    }
    __syncthreads();
  }
  for (int mi = 0; mi < 4; mi++)
    for (int ni = 0; ni < 4; ni++) {
      int col = bcol + wc * 64 + ni * 16 + lr;
      float bb = bias[col];
      for (int r = 0; r < 4; r++) {
        int row = brow + wr * 64 + mi * 16 + lg * 4 + r;
        float v = (acc[mi][ni][r] + bb) * scale;
        C[(size_t)row * 1024 + col] = (short)f2bf(v);
      }
    }
}

// ---------------------------------------------------------------------------
// pos_gemm: per (which,b,h): Out[m,n] = sum_d A[b*1024+m, h*64+d] * B[2048+n, h*64+d]
//   which=0: c2p_att = Q . posK   (A=Qc content rows, B=Kc pos rows)
//   which=1: p2c_att = K . posQ   (A=Kc content rows, B=Qc pos rows)
//   M=1024, N=512, K=64 (single staging). Output bf16 [(b*16+h)*1024+m, 512].
// ---------------------------------------------------------------------------
__global__ __launch_bounds__(256) void pos_gemm(
    const short* __restrict__ Qc, const short* __restrict__ Kc,
    short* __restrict__ c2p, short* __restrict__ p2c) {
  __shared__ short As[128 * 64];
  __shared__ short Bs[128 * 64];
  int tid = threadIdx.x;
  int wid = tid >> 6, lane = tid & 63;
  int lr = lane & 15, lg = lane >> 4;
  int wr = wid >> 1, wc = wid & 1;
  int zz = blockIdx.z;       // 0..63
  int which = zz >> 5;
  int bh = zz & 31;
  int b = bh >> 4, h = bh & 15;
  const short* Arows = (which == 0) ? Qc : Kc;
  const short* Brows = (which == 0) ? Kc : Qc;
  short* Out = (which == 0) ? c2p : p2c;
  int mrow = blockIdx.y * 128;
  int ncol = blockIdx.x * 128;

  for (int i = 0; i < 4; i++) {
    int n = i * 256 + wid * 64 + lane;
    const short* gA = Arows + (size_t)(b * 1024 + mrow + (n >> 3)) * 1024 + h * 64 + (n & 7) * 8;
    gload_lds16(gA, &As[(i * 256 + wid * 64) * 8]);
    const short* gB = Brows + (size_t)(2048 + ncol + (n >> 3)) * 1024 + h * 64 + (n & 7) * 8;
    gload_lds16(gB, &Bs[(i * 256 + wid * 64) * 8]);
  }
  __syncthreads();

  f32x4 acc[4][4];
  for (int i = 0; i < 4; i++)
    for (int j = 0; j < 4; j++) acc[i][j] = (f32x4){0.f, 0.f, 0.f, 0.f};
  for (int ks = 0; ks < 2; ks++) {
    s8v af[4], bfv[4];
    for (int mi = 0; mi < 4; mi++)
      af[mi] = *(const s8v*)&As[(wr * 64 + mi * 16 + lr) * 64 + ks * 32 + lg * 8];
    for (int ni = 0; ni < 4; ni++)
      bfv[ni] = *(const s8v*)&Bs[(wc * 64 + ni * 16 + lr) * 64 + ks * 32 + lg * 8];
    for (int mi = 0; mi < 4; mi++)
      for (int ni = 0; ni < 4; ni++)
        acc[mi][ni] = __builtin_amdgcn_mfma_f32_16x16x32_bf16(
            af[mi], bfv[ni], acc[mi][ni], 0, 0, 0);
  }
  size_t base = (size_t)(b * 16 + h) * 1024;
  for (int mi = 0; mi < 4; mi++)
    for (int ni = 0; ni < 4; ni++)
      for (int r = 0; r < 4; r++) {
        int m = mrow + wr * 64 + mi * 16 + lg * 4 + r;
        int nn = ncol + wc * 64 + ni * 16 + lr;
        Out[(base + m) * 512 + nn] = (short)f2bf(acc[mi][ni][r]);
      }
}

// ---------------------------------------------------------------------------
// transpose_v: Vt[b,h,d,l] = Vc[b*1024+l, h*64+d]  (bf16)
// ---------------------------------------------------------------------------
__global__ __launch_bounds__(256) void transpose_v(
    const short* __restrict__ Vc, short* __restrict__ Vt) {
  __shared__ short TL[64 * 72];
  int tid = threadIdx.x;
  int lt = blockIdx.x, h = blockIdx.y, b = blockIdx.z;
  for (int i = 0; i < 2; i++) {
    int n = i * 256 + tid;
    int l = n >> 3, c = n & 7;
    s8v v = *(const s8v*)&Vc[(size_t)(b * 1024 + lt * 64 + l) * 1024 + h * 64 + c * 8];
    *(s8v*)&TL[l * 72 + c * 8] = v;
  }
  __syncthreads();
  for (int i = 0; i < 2; i++) {
    int m = i * 256 + tid;
    int d = m >> 3, c = m & 7;
    s8v o;
    for (int jj = 0; jj < 8; jj++) o[jj] = TL[(c * 8 + jj) * 72 + d];
    *(s8v*)&Vt[((size_t)(b * 16 + h) * 64 + d) * 1024 + lt * 64 + c * 8] = o;
  }
}

// ---------------------------------------------------------------------------
// attn: per block one (b,h,q-tile of 64). 4 waves x 16 q-rows each.
//   Loop k-tiles of 64: S = Q.K^T (MFMA) + gathered biases -> exp -> P (LDS)
//   -> O += P.Vt^T (MFMA). Unnormalized accumulation; divide by denom at end.
// ---------------------------------------------------------------------------
__global__ __launch_bounds__(256) void attn_kernel(
    const short* __restrict__ Qc, const short* __restrict__ Kc,
    const short* __restrict__ Vt, const short* __restrict__ c2p,
    const short* __restrict__ p2c, const short* __restrict__ Tt,
    const float* __restrict__ mbias, float* __restrict__ out) {
  __shared__ short Kl[64 * 72];
  __shared__ short Vl[64 * 72];
  __shared__ short Pl[4][16 * 72];
  __shared__ short Tl[2048];
  int tid = threadIdx.x;
  int wid = tid >> 6, lane = tid & 63;
  int lr = lane & 15, lg = lane >> 4;
  int qt = blockIdx.x, h = blockIdx.y, b = blockIdx.z;
  int q0 = qt * 64, qbase = q0 + wid * 16;
  size_t bh1024 = (size_t)(b * 16 + h) * 1024;

  for (int i = tid; i < 2047; i += 256) Tl[i] = Tt[i];

  // Q fragments (held in registers for the whole kernel)
  s8v aq[2];
  for (int s_ = 0; s_ < 2; s_++)
    aq[s_] = *(const s8v*)&Qc[(size_t)(b * 1024 + qbase + lr) * 1024 + h * 64 + s_ * 32 + lg * 8];

  f32x4 oacc[4];
  for (int n = 0; n < 4; n++) oacc[n] = (f32x4){0.f, 0.f, 0.f, 0.f};
  float dsum[4] = {0.f, 0.f, 0.f, 0.f};
  __syncthreads();  // Tl ready

  for (int kt = 0; kt < 1024; kt += 64) {
    // stage K and Vt tiles (reg->LDS, padded rows of 72 for even banks)
    for (int i = 0; i < 2; i++) {
      int n = i * 256 + tid;
      int row = n >> 3, c = n & 7;
      s8v kv = *(const s8v*)&Kc[(size_t)(b * 1024 + kt + row) * 1024 + h * 64 + c * 8];
      *(s8v*)&Kl[row * 72 + c * 8] = kv;
      s8v vv = *(const s8v*)&Vt[(bh1024 / 16 * (size_t)0 + (size_t)(b * 16 + h) * 64 + row) * 1024 + kt + c * 8];
      *(s8v*)&Vl[row * 72 + c * 8] = vv;
    }
    __syncthreads();

    // S = Q . K^T  (wave: 16 q x 64 k)
    f32x4 sacc[4];
    for (int n = 0; n < 4; n++) sacc[n] = (f32x4){0.f, 0.f, 0.f, 0.f};
    for (int s_ = 0; s_ < 2; s_++)
      for (int n = 0; n < 4; n++) {
        s8v bk_ = *(const s8v*)&Kl[(n * 16 + lr) * 72 + s_ * 32 + lg * 8];
        sacc[n] = __builtin_amdgcn_mfma_f32_16x16x32_bf16(aq[s_], bk_, sacc[n], 0, 0, 0);
      }

    // bias gather + exp + write P
    for (int n = 0; n < 4; n++) {
      int k = kt + n * 16 + lr;
      float mb = mbias[b * 1024 + k];
      size_t prow = (bh1024 + k) * 512;
      for (int r = 0; r < 4; r++) {
        int q = qbase + lg * 4 + r;
        int idx = Tl[q - k + 1023];
        float bias = bf2f((unsigned short)c2p[(bh1024 + q) * 512 + idx]) +
                     bf2f((unsigned short)p2c[prow + idx]);
        float p = __expf(sacc[n][r] + bias + mb);
        dsum[r] += p;
        Pl[wid][(lg * 4 + r) * 72 + n * 16 + lr] = (short)f2bf(p);
      }
    }
    __syncthreads();

    // O += P . Vt^T  (wave: 16 q x 64 d)
    for (int s_ = 0; s_ < 2; s_++) {
      s8v ap = *(const s8v*)&Pl[wid][lr * 72 + s_ * 32 + lg * 8];
      for (int n = 0; n < 4; n++) {
        s8v bv_ = *(const s8v*)&Vl[(n * 16 + lr) * 72 + s_ * 32 + lg * 8];
        oacc[n] = __builtin_amdgcn_mfma_f32_16x16x32_bf16(ap, bv_, oacc[n], 0, 0, 0);
      }
    }
    __syncthreads();
  }

  // reduce denominators across the 16 lanes sharing the same q rows
  for (int m = 1; m < 16; m <<= 1)
    for (int r = 0; r < 4; r++) dsum[r] += __shfl_xor(dsum[r], m, 64);

  for (int n = 0; n < 4; n++)
    for (int r = 0; r < 4; r++) {
      int q = qbase + lg * 4 + r;
      int d = n * 16 + lr;
      out[(size_t)(b * 1024 + q) * 1024 + h * 64 + d] = oacc[n][r] / dsum[r];
    }
}

// ---------------------------------------------------------------------------
extern "C" void kernel_launch(void* const* d_in, const int* in_sizes, int n_in,
                              void* d_out, int out_size, void* d_ws, size_t ws_size,
                              hipStream_t stream) {
  (void)in_sizes; (void)n_in; (void)out_size; (void)ws_size;
  const float* hidden = (const float*)d_in[0];
  const int* mask = (const int*)d_in[1];
  const float* rel = (const float*)d_in[2];
  const float* Wq = (const float*)d_in[3];
  const float* bq = (const float*)d_in[4];
  const float* Wk = (const float*)d_in[5];
  const float* bk = (const float*)d_in[6];
  const float* Wv = (const float*)d_in[7];
  const float* bv = (const float*)d_in[8];
  float* out = (float*)d_out;

  char* w = (char*)d_ws;
  short* Abf = (short*)w; w += 2560 * 1024 * 2;          // 5.25 MB
  short* Wbf = (short*)w; w += 3 * 1024 * 1024 * 2;      // 6.29 MB
  short* Qc  = (short*)w; w += 2560 * 1024 * 2;
  short* Kc  = (short*)w; w += 2560 * 1024 * 2;
  short* Vc  = (short*)w; w += 2560 * 1024 * 2;
  short* Vt  = (short*)w; w += 2 * 16 * 64 * 1024 * 2;   // 4.19 MB
  short* c2p = (short*)w; w += (size_t)2 * 16 * 1024 * 512 * 2;  // 33.5 MB
  short* p2c = (short*)w; w += (size_t)2 * 16 * 1024 * 512 * 2;  // 33.5 MB
  short* Tt  = (short*)w; w += 4096;
  float* mbias = (float*)w; w += 8192;

  prep_kernel<<<5648, 256, 0, stream>>>(hidden, rel, Wq, Wk, Wv, mask, Abf, Wbf, mbias, Tt);
  gemm_qkv<<<dim3(8, 20, 3), 256, 0, stream>>>(Abf, Wbf, bq, bk, bv, Qc, Kc, Vc);
  pos_gemm<<<dim3(4, 8, 64), 256, 0, stream>>>(Qc, Kc, c2p, p2c);
  transpose_v<<<dim3(16, 16, 2), 256, 0, stream>>>(Vc, Vt);
  attn_kernel<<<dim3(16, 16, 2), 256, 0, stream>>>(Qc, Kc, Vt, c2p, p2c, Tt, mbias, out);
}

// Round 2
// 140.796 us; speedup vs baseline: 1.2161x; 1.2161x over previous
//
#include <hip/hip_runtime.h>

// ---------------------------------------------------------------------------
// DeBERTa-v2 disentangled self-attention, MI355X (gfx950)
// B=2, L=1024, D=1024, H=16, HEAD=64, ATT_SPAN=256 (pos dim 512), scale=sqrt(192)
// ---------------------------------------------------------------------------

typedef short s8v __attribute__((ext_vector_type(8)));
typedef short s4v __attribute__((ext_vector_type(4)));
typedef float f32x4 __attribute__((ext_vector_type(4)));
typedef float f4v __attribute__((ext_vector_type(4)));

#define QK_SCALE 0.26864243f   // 192^(-1/4); folded so all score terms get /sqrt(192)

__device__ __forceinline__ unsigned short f2bf(float f) {
  unsigned u = __builtin_bit_cast(unsigned, f);
  u += 0x7fffu + ((u >> 16) & 1u);          // RNE
  return (unsigned short)(u >> 16);
}
__device__ __forceinline__ float bf2f(unsigned short h) {
  unsigned u = ((unsigned)h) << 16;
  return __builtin_bit_cast(float, u);
}

__device__ __forceinline__ void gload_lds16(const void* g, void* l) {
  __builtin_amdgcn_global_load_lds(
      (const __attribute__((address_space(1))) void*)g,
      (__attribute__((address_space(3))) void*)l, 16, 0, 0);
}

// ---------------------------------------------------------------------------
// prep: f32->bf16 conversions, bucket table, mask bias
// ---------------------------------------------------------------------------
__global__ __launch_bounds__(256) void prep_kernel(
    const float* __restrict__ hidden, const float* __restrict__ rel,
    const float* __restrict__ Wq, const float* __restrict__ Wk,
    const float* __restrict__ Wv, const int* __restrict__ mask,
    short* __restrict__ Abf, short* __restrict__ Wbf,
    float* __restrict__ mbias, short* __restrict__ Tt) {
  int idx = blockIdx.x * 256 + threadIdx.x;
  const int NCONV = 1441792;  // (2560*1024 + 3*1024*1024)/4 float4s
  if (idx < NCONV) {
    const float* src; short* dst; int off;
    if (idx < 524288) { src = hidden; dst = Abf; off = idx; }
    else if (idx < 655360) { src = rel; dst = Abf + 2048 * 1024; off = idx - 524288; }
    else {
      int j = idx - 655360;
      int w = j / 262144; off = j - w * 262144;
      src = (w == 0) ? Wq : (w == 1) ? Wk : Wv;
      dst = Wbf + w * 1048576;
    }
    f4v v = ((const f4v*)src)[off];
    s4v o;
    o[0] = (short)f2bf(v[0]); o[1] = (short)f2bf(v[1]);
    o[2] = (short)f2bf(v[2]); o[3] = (short)f2bf(v[3]);
    ((s4v*)dst)[off] = o;
  } else {
    int j = idx - NCONV;
    if (j < 2047) {
      int r = j - 1023;
      float fr = (float)r;
      float sign = (r > 0) ? 1.f : ((r < 0) ? -1.f : 0.f);
      float abs_pos = (r < 128 && r > -128) ? 127.f : fabsf(fr);
      const float logc = 1.3843393245589053f;  // f32(log(511/128))
      float log_pos = ceilf(logf(abs_pos * (1.f / 128.f)) / logc * 127.f) + 128.f;
      float bucket = (abs_pos <= 128.f) ? fr : log_pos * sign;
      int bi = (int)bucket + 256;
      bi = bi < 0 ? 0 : (bi > 511 ? 511 : bi);
      Tt[j] = (short)bi;
    } else if (j < 4095) {
      int m = j - 2047;
      mbias[m] = (mask[m] > 0) ? 0.f : -1e9f;
    }
  }
}

// ---------------------------------------------------------------------------
// gemm_qkv: C[m,n] = (sum_k A[m,k]*W[n,k] + bias[n]) * scale, bf16 out
// ---------------------------------------------------------------------------
__global__ __launch_bounds__(256) void gemm_qkv(
    const short* __restrict__ Abf, const short* __restrict__ Wbf,
    const float* __restrict__ bq, const float* __restrict__ bk,
    const float* __restrict__ bv,
    short* __restrict__ Qc, short* __restrict__ Kc, short* __restrict__ Vc) {
  __shared__ short As[128 * 64];
  __shared__ short Bs[128 * 64];
  int tid = threadIdx.x;
  int wid = tid >> 6, lane = tid & 63;
  int lr = lane & 15, lg = lane >> 4;
  int wr = wid >> 1, wc = wid & 1;
  int z = blockIdx.z;
  const short* W = Wbf + z * 1048576;
  const float* bias = (z == 0) ? bq : (z == 1) ? bk : bv;
  short* C = (z == 0) ? Qc : (z == 1) ? Kc : Vc;
  float scale = (z == 2) ? 1.f : QK_SCALE;
  int brow = blockIdx.y * 128;
  int bcol = blockIdx.x * 128;

  f32x4 acc[4][4];
  for (int i = 0; i < 4; i++)
    for (int j = 0; j < 4; j++) acc[i][j] = (f32x4){0.f, 0.f, 0.f, 0.f};

  for (int k0 = 0; k0 < 1024; k0 += 64) {
    for (int i = 0; i < 4; i++) {
      int n = i * 256 + wid * 64 + lane;
      const short* gA = Abf + (size_t)(brow + (n >> 3)) * 1024 + k0 + (n & 7) * 8;
      gload_lds16(gA, &As[(i * 256 + wid * 64) * 8]);
      const short* gB = W + (size_t)(bcol + (n >> 3)) * 1024 + k0 + (n & 7) * 8;
      gload_lds16(gB, &Bs[(i * 256 + wid * 64) * 8]);
    }
    __syncthreads();
    for (int ks = 0; ks < 2; ks++) {
      s8v af[4], bfv[4];
      for (int mi = 0; mi < 4; mi++)
        af[mi] = *(const s8v*)&As[(wr * 64 + mi * 16 + lr) * 64 + ks * 32 + lg * 8];
      for (int ni = 0; ni < 4; ni++)
        bfv[ni] = *(const s8v*)&Bs[(wc * 64 + ni * 16 + lr) * 64 + ks * 32 + lg * 8];
      for (int mi = 0; mi < 4; mi++)
        for (int ni = 0; ni < 4; ni++)
          acc[mi][ni] = __builtin_amdgcn_mfma_f32_16x16x32_bf16(
              af[mi], bfv[ni], acc[mi][ni], 0, 0, 0);
    }
    __syncthreads();
  }
  for (int mi = 0; mi < 4; mi++)
    for (int ni = 0; ni < 4; ni++) {
      int col = bcol + wc * 64 + ni * 16 + lr;
      float bb = bias[col];
      for (int r = 0; r < 4; r++) {
        int row = brow + wr * 64 + mi * 16 + lg * 4 + r;
        float v = (acc[mi][ni][r] + bb) * scale;
        C[(size_t)row * 1024 + col] = (short)f2bf(v);
      }
    }
}

// ---------------------------------------------------------------------------
// pos_gemm: per (which,b,h): Out[m,n] = sum_d A[b*1024+m, h*64+d] * B[2048+n, h*64+d]
// ---------------------------------------------------------------------------
__global__ __launch_bounds__(256) void pos_gemm(
    const short* __restrict__ Qc, const short* __restrict__ Kc,
    short* __restrict__ c2p, short* __restrict__ p2c) {
  __shared__ short As[128 * 64];
  __shared__ short Bs[128 * 64];
  int tid = threadIdx.x;
  int wid = tid >> 6, lane = tid & 63;
  int lr = lane & 15, lg = lane >> 4;
  int wr = wid >> 1, wc = wid & 1;
  int zz = blockIdx.z;       // 0..63
  int which = zz >> 5;
  int bh = zz & 31;
  int b = bh >> 4, h = bh & 15;
  const short* Arows = (which == 0) ? Qc : Kc;
  const short* Brows = (which == 0) ? Kc : Qc;
  short* Out = (which == 0) ? c2p : p2c;
  int mrow = blockIdx.y * 128;
  int ncol = blockIdx.x * 128;

  for (int i = 0; i < 4; i++) {
    int n = i * 256 + wid * 64 + lane;
    const short* gA = Arows + (size_t)(b * 1024 + mrow + (n >> 3)) * 1024 + h * 64 + (n & 7) * 8;
    gload_lds16(gA, &As[(i * 256 + wid * 64) * 8]);
    const short* gB = Brows + (size_t)(2048 + ncol + (n >> 3)) * 1024 + h * 64 + (n & 7) * 8;
    gload_lds16(gB, &Bs[(i * 256 + wid * 64) * 8]);
  }
  __syncthreads();

  f32x4 acc[4][4];
  for (int i = 0; i < 4; i++)
    for (int j = 0; j < 4; j++) acc[i][j] = (f32x4){0.f, 0.f, 0.f, 0.f};
  for (int ks = 0; ks < 2; ks++) {
    s8v af[4], bfv[4];
    for (int mi = 0; mi < 4; mi++)
      af[mi] = *(const s8v*)&As[(wr * 64 + mi * 16 + lr) * 64 + ks * 32 + lg * 8];
    for (int ni = 0; ni < 4; ni++)
      bfv[ni] = *(const s8v*)&Bs[(wc * 64 + ni * 16 + lr) * 64 + ks * 32 + lg * 8];
    for (int mi = 0; mi < 4; mi++)
      for (int ni = 0; ni < 4; ni++)
        acc[mi][ni] = __builtin_amdgcn_mfma_f32_16x16x32_bf16(
            af[mi], bfv[ni], acc[mi][ni], 0, 0, 0);
  }
  size_t base = (size_t)(b * 16 + h) * 1024;
  for (int mi = 0; mi < 4; mi++)
    for (int ni = 0; ni < 4; ni++)
      for (int r = 0; r < 4; r++) {
        int m = mrow + wr * 64 + mi * 16 + lg * 4 + r;
        int nn = ncol + wc * 64 + ni * 16 + lr;
        Out[(base + m) * 512 + nn] = (short)f2bf(acc[mi][ni][r]);
      }
}

// ---------------------------------------------------------------------------
// transpose_v: Vt[b,h,d,l] = Vc[b*1024+l, h*64+d]  (bf16)
// ---------------------------------------------------------------------------
__global__ __launch_bounds__(256) void transpose_v(
    const short* __restrict__ Vc, short* __restrict__ Vt) {
  __shared__ short TL[64 * 72];
  int tid = threadIdx.x;
  int lt = blockIdx.x, h = blockIdx.y, b = blockIdx.z;
  for (int i = 0; i < 2; i++) {
    int n = i * 256 + tid;
    int l = n >> 3, c = n & 7;
    s8v v = *(const s8v*)&Vc[(size_t)(b * 1024 + lt * 64 + l) * 1024 + h * 64 + c * 8];
    *(s8v*)&TL[l * 72 + c * 8] = v;
  }
  __syncthreads();
  for (int i = 0; i < 2; i++) {
    int m = i * 256 + tid;
    int d = m >> 3, c = m & 7;
    s8v o;
    for (int jj = 0; jj < 8; jj++) o[jj] = TL[(c * 8 + jj) * 72 + d];
    *(s8v*)&Vt[((size_t)(b * 16 + h) * 64 + d) * 1024 + lt * 64 + c * 8] = o;
  }
}

// ---------------------------------------------------------------------------
// attn: block = (b, h, 64-q tile, K-segment of 1024/NSPLIT). 4 waves x 16 q.
//   Max-free softmax: partial (unnormalized O, denom) per segment add across
//   segments -> combine kernel. K/V tiles XOR-swizzled in LDS (no padding).
// ---------------------------------------------------------------------------
template <int NSPLIT>
__global__ __launch_bounds__(256) void attn_kernel(
    const short* __restrict__ Qc, const short* __restrict__ Kc,
    const short* __restrict__ Vt, const short* __restrict__ c2p,
    const short* __restrict__ p2c, const short* __restrict__ Tt,
    const float* __restrict__ mbias, float* __restrict__ Opart,
    float* __restrict__ dpart, float* __restrict__ out) {
  const int KSEG = 1024 / NSPLIT;
  const int TLN = 64 + KSEG - 1;
  __shared__ short Kl[64 * 64];
  __shared__ short Vl[64 * 64];
  __shared__ short Pl[4][16 * 72];
  __shared__ short Tl[TLN + 1];
  int tid = threadIdx.x;
  int wid = tid >> 6, lane = tid & 63;
  int lr = lane & 15, lg = lane >> 4;
  int qt = blockIdx.x, h = blockIdx.y, z = blockIdx.z;
  int b = (NSPLIT == 1) ? z : (z >> 2);
  int ks = (NSPLIT == 1) ? 0 : (z & 3);
  int k0seg = ks * KSEG;
  int q0 = qt * 64, qbase = q0 + wid * 16;
  size_t bh1024 = (size_t)(b * 16 + h) * 1024;

  // bucket-table slice for rel = q-k, q in [q0,q0+64), k in [k0seg,k0seg+KSEG)
  for (int i = tid; i < TLN; i += 256) Tl[i] = Tt[(q0 - k0seg - (KSEG - 1) + 1023) + i];

  // Q fragments (held in registers for the whole kernel)
  s8v aq[2];
  for (int s_ = 0; s_ < 2; s_++)
    aq[s_] = *(const s8v*)&Qc[(size_t)(b * 1024 + qbase + lr) * 1024 + h * 64 + s_ * 32 + lg * 8];

  f32x4 oacc[4];
  for (int n = 0; n < 4; n++) oacc[n] = (f32x4){0.f, 0.f, 0.f, 0.f};
  float dsum[4] = {0.f, 0.f, 0.f, 0.f};
  __syncthreads();  // Tl ready

  for (int kt = k0seg; kt < k0seg + KSEG; kt += 64) {
    // stage K and Vt tiles, reg->LDS, XOR swizzle (16B granule)
    for (int i = 0; i < 2; i++) {
      int n = i * 256 + tid;
      int row = n >> 3, cb = n & 7, cbs = cb ^ (row & 7);
      s8v kv = *(const s8v*)&Kc[(size_t)(b * 1024 + kt + row) * 1024 + h * 64 + cb * 8];
      *(s8v*)&Kl[row * 64 + cbs * 8] = kv;
      s8v vv = *(const s8v*)&Vt[((size_t)(b * 16 + h) * 64 + row) * 1024 + kt + cb * 8];
      *(s8v*)&Vl[row * 64 + cbs * 8] = vv;
    }
    __syncthreads();

    // S = Q . K^T  (wave: 16 q x 64 k)
    f32x4 sacc[4];
    for (int n = 0; n < 4; n++) sacc[n] = (f32x4){0.f, 0.f, 0.f, 0.f};
    for (int s_ = 0; s_ < 2; s_++)
      for (int n = 0; n < 4; n++) {
        int row = n * 16 + lr, cb = s_ * 4 + lg, cbs = cb ^ (row & 7);
        s8v bk_ = *(const s8v*)&Kl[row * 64 + cbs * 8];
        sacc[n] = __builtin_amdgcn_mfma_f32_16x16x32_bf16(aq[s_], bk_, sacc[n], 0, 0, 0);
      }

    // bias gathers: batch loads, then exp
    float c2v[4][4], p2v[4][4], mbv[4];
    int ktl = kt - k0seg;
    int jb = (qbase - q0) - ktl - lr + (KSEG - 1);
    for (int n = 0; n < 4; n++) {
      int k = kt + n * 16 + lr;
      mbv[n] = mbias[b * 1024 + k];
      size_t prow = (bh1024 + k) * 512;
      for (int r = 0; r < 4; r++) {
        int q = qbase + lg * 4 + r;
        int idx = Tl[jb + lg * 4 + r - n * 16];
        c2v[n][r] = bf2f((unsigned short)c2p[(bh1024 + q) * 512 + idx]);
        p2v[n][r] = bf2f((unsigned short)p2c[prow + idx]);
      }
    }
    for (int n = 0; n < 4; n++)
      for (int r = 0; r < 4; r++) {
        float p = __expf(sacc[n][r] + c2v[n][r] + p2v[n][r] + mbv[n]);
        dsum[r] += p;
        Pl[wid][(lg * 4 + r) * 72 + n * 16 + lr] = (short)f2bf(p);
      }
    __syncthreads();

    // O += P . Vt^T  (wave: 16 q x 64 d)
    for (int s_ = 0; s_ < 2; s_++) {
      s8v ap = *(const s8v*)&Pl[wid][lr * 72 + s_ * 32 + lg * 8];
      for (int n = 0; n < 4; n++) {
        int row = n * 16 + lr, cb = s_ * 4 + lg, cbs = cb ^ (row & 7);
        s8v bv_ = *(const s8v*)&Vl[row * 64 + cbs * 8];
        oacc[n] = __builtin_amdgcn_mfma_f32_16x16x32_bf16(ap, bv_, oacc[n], 0, 0, 0);
      }
    }
    __syncthreads();
  }

  // reduce denominators across the 16 lanes (lr) sharing the same q rows
  for (int m = 1; m < 16; m <<= 1)
    for (int r = 0; r < 4; r++) dsum[r] += __shfl_xor(dsum[r], m, 64);

  if (NSPLIT == 1) {
    for (int n = 0; n < 4; n++)
      for (int r = 0; r < 4; r++) {
        int q = qbase + lg * 4 + r;
        int d = n * 16 + lr;
        out[(size_t)(b * 1024 + q) * 1024 + h * 64 + d] = oacc[n][r] / dsum[r];
      }
  } else {
    size_t po = ((size_t)(z * 16 + h)) * 65536;
    for (int n = 0; n < 4; n++)
      for (int r = 0; r < 4; r++) {
        int q = qbase + lg * 4 + r;
        Opart[po + (size_t)q * 64 + n * 16 + lr] = oacc[n][r];
      }
    if (lr == 0)
      for (int r = 0; r < 4; r++)
        dpart[(z * 16 + h) * 1024 + qbase + lg * 4 + r] = dsum[r];
  }
}

// ---------------------------------------------------------------------------
// combine: out = sum_ks Opart / sum_ks dpart
// ---------------------------------------------------------------------------
__global__ __launch_bounds__(256) void combine_kernel(
    const float* __restrict__ Opart, const float* __restrict__ dpart,
    float* __restrict__ out) {
  int idx = blockIdx.x * 256 + threadIdx.x;
  int pos = idx * 4;                 // flat out index, 4 floats per thread
  int b = pos >> 20;
  int q = (pos >> 10) & 1023;
  int hd = pos & 1023;
  int h = hd >> 6, d = hd & 63;
  f4v s = (f4v){0.f, 0.f, 0.f, 0.f};
  float dn = 0.f;
  for (int ks = 0; ks < 4; ks++) {
    int zh = (b * 4 + ks) * 16 + h;
    s += *(const f4v*)&Opart[(size_t)zh * 65536 + q * 64 + d];
    dn += dpart[zh * 1024 + q];
  }
  f4v r = s / dn;
  *(f4v*)&out[pos] = r;
}

// ---------------------------------------------------------------------------
extern "C" void kernel_launch(void* const* d_in, const int* in_sizes, int n_in,
                              void* d_out, int out_size, void* d_ws, size_t ws_size,
                              hipStream_t stream) {
  (void)in_sizes; (void)n_in; (void)out_size;
  const float* hidden = (const float*)d_in[0];
  const int* mask = (const int*)d_in[1];
  const float* rel = (const float*)d_in[2];
  const float* Wq = (const float*)d_in[3];
  const float* bq = (const float*)d_in[4];
  const float* Wk = (const float*)d_in[5];
  const float* bk = (const float*)d_in[6];
  const float* Wv = (const float*)d_in[7];
  const float* bv = (const float*)d_in[8];
  float* out = (float*)d_out;

  char* w = (char*)d_ws;
  short* Abf = (short*)w; w += 2560 * 1024 * 2;          // 5.25 MB
  short* Wbf = (short*)w; w += 3 * 1024 * 1024 * 2;      // 6.29 MB
  short* Qc  = (short*)w; w += 2560 * 1024 * 2;
  short* Kc  = (short*)w; w += 2560 * 1024 * 2;
  short* Vc  = (short*)w; w += 2560 * 1024 * 2;
  short* Vt  = (short*)w; w += 2 * 16 * 64 * 1024 * 2;   // 4.19 MB
  short* c2p = (short*)w; w += (size_t)2 * 16 * 1024 * 512 * 2;  // 33.5 MB
  short* p2c = (short*)w; w += (size_t)2 * 16 * 1024 * 512 * 2;  // 33.5 MB
  short* Tt  = (short*)w; w += 4096;
  float* mbias = (float*)w; w += 8192;
  float* Opart = (float*)w; w += (size_t)8 * 16 * 1024 * 64 * 4;  // 33.5 MB
  float* dpart = (float*)w; w += 8 * 16 * 1024 * 4;               // 0.5 MB
  size_t need = (size_t)(w - (char*)d_ws);

  prep_kernel<<<5648, 256, 0, stream>>>(hidden, rel, Wq, Wk, Wv, mask, Abf, Wbf, mbias, Tt);
  gemm_qkv<<<dim3(8, 20, 3), 256, 0, stream>>>(Abf, Wbf, bq, bk, bv, Qc, Kc, Vc);
  pos_gemm<<<dim3(4, 8, 64), 256, 0, stream>>>(Qc, Kc, c2p, p2c);
  transpose_v<<<dim3(16, 16, 2), 256, 0, stream>>>(Vc, Vt);
  if (ws_size >= need) {
    attn_kernel<4><<<dim3(16, 16, 8), 256, 0, stream>>>(Qc, Kc, Vt, c2p, p2c, Tt,
                                                        mbias, Opart, dpart, out);
    combine_kernel<<<2048, 256, 0, stream>>>(Opart, dpart, out);
  } else {
    attn_kernel<1><<<dim3(16, 16, 2), 256, 0, stream>>>(Qc, Kc, Vt, c2p, p2c, Tt,
                                                        mbias, Opart, dpart, out);
  }
}